// Round 3
// baseline (813.986 us; speedup 1.0000x reference)
//
#include <hip/hip_runtime.h>

#define DEG 10
#define KK  11      // DEG+1 coefficients
#define DV  12      // number of variables
#define NP  66      // D*(D-1)/2 pairs
#define BLK 256
#define SPT 4       // samples per thread

__device__ __constant__ float c_binom[KK] =
    {1.f, 10.f, 45.f, 120.f, 210.f, 252.f, 210.f, 120.f, 45.f, 10.f, 1.f};

__global__ __launch_bounds__(BLK)
void decor_kernel(const float* __restrict__ in,
                  const float* __restrict__ params,
                  const float* __restrict__ pr,
                  float* __restrict__ out,
                  int n)
{
    // params transposed to [pair][k], padded to 12 floats/row (48B, float4-aligned),
    // with binomial coefficients pre-folded.
    __shared__ float sp[NP][12];
    __shared__ float sa[DV];   // t = fma(x, sa[c], sb[c])
    __shared__ float sb[DV];

    const int tid = threadIdx.x;

    for (int i = tid; i < KK * NP; i += BLK) {
        int k = i / NP;
        int p = i - k * NP;
        sp[p][k] = params[i] * c_binom[k];
    }
    if (tid < NP) sp[tid][11] = 0.0f;   // pad lane (never used in math)
    if (tid < DV) {
        float low  = pr[tid];
        float high = pr[DV + tid];
        float w    = high - low;
        float lo   = low - 0.1f * w;
        float hi   = high + 0.1f * w;
        float inv  = 1.0f / (hi - lo);
        sa[tid] = inv;
        sb[tid] = -lo * inv;
    }
    __syncthreads();

    const int base = blockIdx.x * (BLK * SPT) + tid;

    float x[SPT][DV];
    float acc[SPT][DV];
    bool  valid[SPT];

    const float4* in4 = (const float4*)in;
#pragma unroll
    for (int s = 0; s < SPT; ++s) {
        const int row = base + s * BLK;
        valid[s] = (row < n);
        float4 r0, r1, r2;
        if (valid[s]) {
            r0 = in4[(size_t)row * 3 + 0];
            r1 = in4[(size_t)row * 3 + 1];
            r2 = in4[(size_t)row * 3 + 2];
        } else {
            r0 = make_float4(0.f, 0.f, 0.f, 0.f);
            r1 = r0; r2 = r0;
        }
        x[s][0] = r0.x; x[s][1] = r0.y; x[s][2]  = r0.z; x[s][3]  = r0.w;
        x[s][4] = r1.x; x[s][5] = r1.y; x[s][6]  = r1.z; x[s][7]  = r1.w;
        x[s][8] = r2.x; x[s][9] = r2.y; x[s][10] = r2.z; x[s][11] = r2.w;
#pragma unroll
        for (int v = 0; v < DV; ++v) acc[s][v] = x[s][v];
    }

#pragma unroll
    for (int c = 0; c < DV - 1; ++c) {
        // Bernstein basis per sample (binom folded into params; x[c] folded in)
        float b[SPT][KK];
#pragma unroll
        for (int s = 0; s < SPT; ++s) {
            float t = __builtin_fmaf(x[s][c], sa[c], sb[c]);
            float u = 1.0f - t;
            b[s][0] = 1.0f;
#pragma unroll
            for (int k = 1; k < KK; ++k) b[s][k] = b[s][k - 1] * t;
            float q = x[s][c];
#pragma unroll
            for (int k = KK - 1; k >= 0; --k) { b[s][k] *= q; q *= u; }
        }

#pragma unroll
        for (int v = c + 1; v < DV; ++v) {
            const float* w = sp[v * (v - 1) / 2 + c];
            float4 w0 = *(const float4*)(w + 0);
            float4 w1 = *(const float4*)(w + 4);
            float4 w2 = *(const float4*)(w + 8);
#pragma unroll
            for (int s = 0; s < SPT; ++s) {
                float a = acc[s][v];
                a = __builtin_fmaf(b[s][0],  w0.x, a);
                a = __builtin_fmaf(b[s][1],  w0.y, a);
                a = __builtin_fmaf(b[s][2],  w0.z, a);
                a = __builtin_fmaf(b[s][3],  w0.w, a);
                a = __builtin_fmaf(b[s][4],  w1.x, a);
                a = __builtin_fmaf(b[s][5],  w1.y, a);
                a = __builtin_fmaf(b[s][6],  w1.z, a);
                a = __builtin_fmaf(b[s][7],  w1.w, a);
                a = __builtin_fmaf(b[s][8],  w2.x, a);
                a = __builtin_fmaf(b[s][9],  w2.y, a);
                a = __builtin_fmaf(b[s][10], w2.z, a);
                acc[s][v] = a;
            }
        }
    }

    float4* out4 = (float4*)out;
#pragma unroll
    for (int s = 0; s < SPT; ++s) {
        if (valid[s]) {
            const int row = base + s * BLK;
            float4 o0 = {acc[s][0], acc[s][1], acc[s][2],  acc[s][3]};
            float4 o1 = {acc[s][4], acc[s][5], acc[s][6],  acc[s][7]};
            float4 o2 = {acc[s][8], acc[s][9], acc[s][10], acc[s][11]};
            out4[(size_t)row * 3 + 0] = o0;
            out4[(size_t)row * 3 + 1] = o1;
            out4[(size_t)row * 3 + 2] = o2;
        }
    }
}

extern "C" void kernel_launch(void* const* d_in, const int* in_sizes, int n_in,
                              void* d_out, int out_size, void* d_ws, size_t ws_size,
                              hipStream_t stream)
{
    const float* in     = (const float*)d_in[0];   // [N, 12] fp32
    const float* params = (const float*)d_in[1];   // [11, 66] fp32
    const float* pr     = (const float*)d_in[2];   // [2, 12] fp32
    float* out          = (float*)d_out;           // [N, 12] fp32

    const int n = in_sizes[0] / DV;                // number of samples
    const int grid = (n + BLK * SPT - 1) / (BLK * SPT);
    decor_kernel<<<grid, BLK, 0, stream>>>(in, params, pr, out, n);
}

// Round 4
// 119.302 us; speedup vs baseline: 6.8229x; 6.8229x over previous
//
#include <hip/hip_runtime.h>

#define DEG 10
#define KK  11      // DEG+1 coefficients
#define DV  12      // number of variables
#define NP  66      // D*(D-1)/2 pairs
#define BLK 256

// d_ws layout (floats):
//   [0 .. 791]   W[66][12]: per-pair coeffs, transposed, binom-folded, 12th = pad
//   [792 .. 803] sa[12]  (t = fma(x, sa[c], sb[c]))
//   [804 .. 815] sb[12]
#define W_OFF  0
#define SA_OFF (NP * 12)
#define SB_OFF (NP * 12 + DV)

__device__ __constant__ float c_binom[KK] =
    {1.f, 10.f, 45.f, 120.f, 210.f, 252.f, 210.f, 120.f, 45.f, 10.f, 1.f};

__global__ __launch_bounds__(BLK)
void prep_kernel(const float* __restrict__ params,
                 const float* __restrict__ pr,
                 float* __restrict__ ws)
{
    const int tid = threadIdx.x;
    for (int i = tid; i < NP * 12; i += BLK) {
        const int p = i / 12;
        const int k = i - p * 12;
        ws[W_OFF + i] = (k < KK) ? params[k * NP + p] * c_binom[k] : 0.0f;
    }
    if (tid < DV) {
        float low  = pr[tid];
        float high = pr[DV + tid];
        float w    = high - low;
        float lo   = low - 0.1f * w;
        float hi   = high + 0.1f * w;
        float inv  = 1.0f / (hi - lo);
        ws[SA_OFF + tid] = inv;
        ws[SB_OFF + tid] = -lo * inv;
    }
}

__global__ __launch_bounds__(BLK)
void decor_kernel(const float* __restrict__ in,
                  const float* __restrict__ wsp,   // prep output: all wave-uniform
                  float* __restrict__ out,
                  int n)
{
    const int idx = blockIdx.x * BLK + threadIdx.x;
    if (idx >= n) return;

    const float4* in4 = (const float4*)in;
    float4 r0 = in4[(size_t)idx * 3 + 0];
    float4 r1 = in4[(size_t)idx * 3 + 1];
    float4 r2 = in4[(size_t)idx * 3 + 2];

    float x[DV];
    x[0] = r0.x; x[1] = r0.y; x[2]  = r0.z; x[3]  = r0.w;
    x[4] = r1.x; x[5] = r1.y; x[6]  = r1.z; x[7]  = r1.w;
    x[8] = r2.x; x[9] = r2.y; x[10] = r2.z; x[11] = r2.w;

    float acc[DV];
#pragma unroll
    for (int v = 0; v < DV; ++v) acc[v] = x[v];

#pragma unroll
    for (int c = 0; c < DV - 1; ++c) {
        // wsp[SA_OFF+c] / wsp[SB_OFF+c]: uniform address, compile-time offset
        float t = __builtin_fmaf(x[c], wsp[SA_OFF + c], wsp[SB_OFF + c]);
        float u = 1.0f - t;

        // Bernstein basis, binom pre-folded into W, x[c] folded into q-pass
        float b[KK];
        b[0] = 1.0f;
#pragma unroll
        for (int k = 1; k < KK; ++k) b[k] = b[k - 1] * t;
        float q = x[c];
#pragma unroll
        for (int k = KK - 1; k >= 0; --k) { b[k] *= q; q *= u; }

#pragma unroll
        for (int v = c + 1; v < DV; ++v) {
            // uniform, compile-time-indexed coefficient reads -> SMEM s_load,
            // consumed as SGPR operands by the FMAs (no LDS, no VMEM)
            const float* w = wsp + W_OFF + (v * (v - 1) / 2 + c) * 12;
            float a = acc[v];
            a = __builtin_fmaf(b[0],  w[0],  a);
            a = __builtin_fmaf(b[1],  w[1],  a);
            a = __builtin_fmaf(b[2],  w[2],  a);
            a = __builtin_fmaf(b[3],  w[3],  a);
            a = __builtin_fmaf(b[4],  w[4],  a);
            a = __builtin_fmaf(b[5],  w[5],  a);
            a = __builtin_fmaf(b[6],  w[6],  a);
            a = __builtin_fmaf(b[7],  w[7],  a);
            a = __builtin_fmaf(b[8],  w[8],  a);
            a = __builtin_fmaf(b[9],  w[9],  a);
            a = __builtin_fmaf(b[10], w[10], a);
            acc[v] = a;
        }
    }

    float4 o0 = {acc[0], acc[1], acc[2],  acc[3]};
    float4 o1 = {acc[4], acc[5], acc[6],  acc[7]};
    float4 o2 = {acc[8], acc[9], acc[10], acc[11]};
    float4* out4 = (float4*)out;
    out4[(size_t)idx * 3 + 0] = o0;
    out4[(size_t)idx * 3 + 1] = o1;
    out4[(size_t)idx * 3 + 2] = o2;
}

extern "C" void kernel_launch(void* const* d_in, const int* in_sizes, int n_in,
                              void* d_out, int out_size, void* d_ws, size_t ws_size,
                              hipStream_t stream)
{
    const float* in     = (const float*)d_in[0];   // [N, 12] fp32
    const float* params = (const float*)d_in[1];   // [11, 66] fp32
    const float* pr     = (const float*)d_in[2];   // [2, 12] fp32
    float* out          = (float*)d_out;           // [N, 12] fp32
    float* ws           = (float*)d_ws;

    const int n = in_sizes[0] / DV;                // number of samples

    prep_kernel<<<1, BLK, 0, stream>>>(params, pr, ws);
    const int grid = (n + BLK - 1) / BLK;
    decor_kernel<<<grid, BLK, 0, stream>>>(in, ws, out, n);
}